// Round 1
// baseline (118.413 us; speedup 1.0000x reference)
//
#include <hip/hip_runtime.h>

#define NE     100000
#define NR     64
#define DIM    16
#define NHOP   2
#define NMEM   32
#define NNODES 16384

// Transposed relation table in LDS, bf16.
// Row (r,e) holds R[r][d][e] for d=0..15 (i.e. column e of R[r]), 16 ushorts.
// Pitch 20 ushorts (40B) per row -> lane-e starts at bank (10e mod 32): all 16
// distinct, 8B chunks tile with zero overlap within a 16-lane group.
// Per-r pitch 328 ushorts (656B) -> +4 bank stagger per r to decorrelate groups.
#define RPITCH_E 20
#define RPITCH_R 328

__device__ __forceinline__ float bflo(unsigned u) {
    union { unsigned i; float f; } c; c.i = u << 16; return c.f;
}
__device__ __forceinline__ float bfhi(unsigned u) {
    union { unsigned i; float f; } c; c.i = u & 0xffff0000u; return c.f;
}
__device__ __forceinline__ unsigned short f2bf(float f) {
    union { float f; unsigned u; } c; c.f = f;
    unsigned u = c.u;
    unsigned r = (u + 0x7fffu + ((u >> 16) & 1u)) >> 16;  // round-to-nearest-even
    return (unsigned short)r;
}

// Sum across 16 contiguous lanes, result broadcast to all 16. Pure DPP (VALU),
// no LDS-pipe traffic: xor1, xor2 via quad_perm; then row_ror:4 + row_ror:8
// complete the 4-quad cyclic reduction.
__device__ __forceinline__ float dpp_sum16(float v) {
    union { int i; float f; } a, b;
    a.f = v;
    b.i = __builtin_amdgcn_update_dpp(0, a.i, 0xB1,  0xf, 0xf, true); a.f += b.f; // quad_perm [1,0,3,2]
    b.i = __builtin_amdgcn_update_dpp(0, a.i, 0x4E,  0xf, 0xf, true); a.f += b.f; // quad_perm [2,3,0,1]
    b.i = __builtin_amdgcn_update_dpp(0, a.i, 0x124, 0xf, 0xf, true); a.f += b.f; // row_ror:4
    b.i = __builtin_amdgcn_update_dpp(0, a.i, 0x128, 0xf, 0xf, true); a.f += b.f; // row_ror:8
    return a.f;
}

extern "C" __global__ void __launch_bounds__(256)
ripple_kernel(const int* __restrict__ nodes,
              const int* __restrict__ mh,
              const int* __restrict__ mr,
              const int* __restrict__ mt,
              const float* __restrict__ ent,
              const float* __restrict__ rel,
              const float* __restrict__ W,
              float* __restrict__ out)
{
    __shared__ __align__(16) unsigned short rt[NR * RPITCH_R]; // 41984 B

    const int tid = threadIdx.x;

    // ---- Stage relation_emb (64 x 256 fp32) transposed+bf16 into LDS ----
    {
        const float4* rel4 = (const float4*)rel;
        #pragma unroll
        for (int i = 0; i < 16; ++i) {
            int vidx = i * 256 + tid;           // 4096 float4s total
            float4 v = rel4[vidx];
            int k0 = vidx * 4;                  // flat fp32 index
            int r = k0 >> 8;
            int k = k0 & 255;
            int d = k >> 4;
            int e = k & 15;                     // e % 4 == 0, no row wrap
            unsigned short* base = &rt[r * RPITCH_R + d];
            base[(e + 0) * RPITCH_E] = f2bf(v.x);
            base[(e + 1) * RPITCH_E] = f2bf(v.y);
            base[(e + 2) * RPITCH_E] = f2bf(v.z);
            base[(e + 3) * RPITCH_E] = f2bf(v.w);
        }
    }
    __syncthreads();

    const int lane = tid & 63;
    const int wid  = tid >> 6;
    const int g    = lane >> 4;   // mem-group 0..3
    const int e    = lane & 15;   // dim index
    const int n    = blockIdx.x * 4 + wid;

    // W row e (item' = (item+o) @ W.T  =>  item'[e] = sum_d v[d]*W[e][d])
    float Wr[16];
    {
        const float4* wr4 = (const float4*)(W + e * DIM);
        #pragma unroll
        for (int j = 0; j < 4; ++j) {
            float4 w = wr4[j];
            Wr[4 * j + 0] = w.x; Wr[4 * j + 1] = w.y;
            Wr[4 * j + 2] = w.z; Wr[4 * j + 3] = w.w;
        }
    }

    float item    = ent[nodes[n] * DIM + e];
    float out_acc = 0.f;

    #pragma unroll
    for (int hop = 0; hop < NHOP; ++hop) {
        // broadcast item vector to every lane (16 regs)
        float itm[16];
        #pragma unroll
        for (int d = 0; d < 16; ++d) itm[d] = __shfl(item, d, 16);

        const int ibase = hop * (NNODES * NMEM) + n * NMEM;
        float sc[8], tv[8];

        #pragma unroll
        for (int it = 0; it < 8; ++it) {
            const int m    = it * 4 + g;
            const int hidx = mh[ibase + m];
            const int ridx = mr[ibase + m];
            const int tidx = mt[ibase + m];

            // q_e = sum_d R[d][e] * item[d]   (reads transposed LDS row)
            const uint2* row = (const uint2*)&rt[ridx * RPITCH_R + e * RPITCH_E];
            float q = 0.f;
            #pragma unroll
            for (int j = 0; j < 4; ++j) {
                uint2 u = row[j];
                q += itm[4 * j + 0] * bflo(u.x) + itm[4 * j + 1] * bfhi(u.x)
                   + itm[4 * j + 2] * bflo(u.y) + itm[4 * j + 3] * bfhi(u.y);
            }
            float he = ent[hidx * DIM + e];
            sc[it] = dpp_sum16(q * he);        // score_m = item . (R @ h)
            tv[it] = ent[tidx * DIM + e];
        }

        // softmax over the 32 memory slots
        float mx = sc[0];
        #pragma unroll
        for (int it = 1; it < 8; ++it) mx = fmaxf(mx, sc[it]);
        mx = fmaxf(mx, __shfl_xor(mx, 16));
        mx = fmaxf(mx, __shfl_xor(mx, 32));

        float ex[8], Z = 0.f;
        #pragma unroll
        for (int it = 0; it < 8; ++it) { ex[it] = __expf(sc[it] - mx); Z += ex[it]; }
        Z += __shfl_xor(Z, 16);
        Z += __shfl_xor(Z, 32);
        const float inv = 1.f / Z;

        // o[e] = sum_m p_m * t_m[e]
        float o = 0.f;
        #pragma unroll
        for (int it = 0; it < 8; ++it) o += ex[it] * tv[it];
        o *= inv;
        o += __shfl_xor(o, 16);
        o += __shfl_xor(o, 32);

        out_acc += (hop == 0) ? 2.f * o : o;   // faithful: result = o1 + 2*o0

        // item = (item + o) @ W.T
        const float v = item + o;
        float nit = 0.f;
        #pragma unroll
        for (int d = 0; d < 16; ++d) nit += Wr[d] * __shfl(v, d, 16);
        item = nit;
    }

    if (lane < 16) out[n * DIM + e] = out_acc;
}

extern "C" void kernel_launch(void* const* d_in, const int* in_sizes, int n_in,
                              void* d_out, int out_size, void* d_ws, size_t ws_size,
                              hipStream_t stream) {
    const int*   nodes = (const int*)d_in[0];
    const int*   mh    = (const int*)d_in[1];
    const int*   mr    = (const int*)d_in[2];
    const int*   mt    = (const int*)d_in[3];
    const float* ent   = (const float*)d_in[4];
    const float* rel   = (const float*)d_in[5];
    const float* W     = (const float*)d_in[6];
    float*       out   = (float*)d_out;

    dim3 grid(NNODES / 4);   // 1 wave per node, 4 nodes per 256-thread block
    dim3 block(256);
    ripple_kernel<<<grid, block, 0, stream>>>(nodes, mh, mr, mt, ent, rel, W, out);
}

// Round 2
// 102.035 us; speedup vs baseline: 1.1605x; 1.1605x over previous
//
#include <hip/hip_runtime.h>

#define NE     100000
#define NR     64
#define DIM    16
#define NHOP   2
#define NMEM   32
#define NNODES 16384

// Relation table in LDS: bf16, transposed (row (r,e) holds column e of R[r],
// i.e. R[r][d][e], d=0..15), packed with ZERO padding (64*256 ushorts = 32 KB)
// and an XOR chunk swizzle for bank-conflict freedom:
//   row (r,e) = 4 chunks of 4 d-values (8 B each); logical chunk c lives at
//   phys slot (c + (e>>2)) & 3.  Read instr j: lane e hits banks
//   {8(e&3)*?}: bank = (8e + 2((j+(e>>2))&3)) mod 32 = 8*(e&3) + 2*((j+e>>2)&3)
//   -> 4 disjoint bank groups x 4 disjoint offsets -> 16 lanes conflict-free.
#define WPITCH 20   // W staging pitch in floats (80 B): 2-way max -> free

static __device__ __forceinline__ float bflo(unsigned u) {
    union { unsigned i; float f; } c; c.i = u << 16; return c.f;
}
static __device__ __forceinline__ float bfhi(unsigned u) {
    union { unsigned i; float f; } c; c.i = u & 0xffff0000u; return c.f;
}
static __device__ __forceinline__ unsigned short f2bf(float f) {
    union { float f; unsigned u; } c; c.f = f;
    unsigned u = c.u;
    return (unsigned short)((u + 0x7fffu + ((u >> 16) & 1u)) >> 16); // RNE
}

// Sum across 16 contiguous lanes, broadcast to all 16. Pure DPP (VALU pipe).
static __device__ __forceinline__ float dpp_sum16(float v) {
    union { int i; float f; } a, b;
    a.f = v;
    b.i = __builtin_amdgcn_update_dpp(0, a.i, 0xB1,  0xf, 0xf, true); a.f += b.f; // quad_perm [1,0,3,2]
    b.i = __builtin_amdgcn_update_dpp(0, a.i, 0x4E,  0xf, 0xf, true); a.f += b.f; // quad_perm [2,3,0,1]
    b.i = __builtin_amdgcn_update_dpp(0, a.i, 0x124, 0xf, 0xf, true); a.f += b.f; // row_ror:4
    b.i = __builtin_amdgcn_update_dpp(0, a.i, 0x128, 0xf, 0xf, true); a.f += b.f; // row_ror:8
    return a.f;
}

// Wave-uniform broadcast into an SGPR (item vector is per-node = per-wave).
static __device__ __forceinline__ float bcast(float v, int l) {
    return __int_as_float(__builtin_amdgcn_readlane(__float_as_int(v), l));
}

extern "C" __global__ void __launch_bounds__(512, 8)
ripple_kernel(const int* __restrict__ nodes,
              const int* __restrict__ mh,
              const int* __restrict__ mr,
              const int* __restrict__ mt,
              const float* __restrict__ ent,
              const float* __restrict__ rel,
              const float* __restrict__ W,
              float* __restrict__ out)
{
    __shared__ __align__(16) unsigned short rt[NR * 256];   // 32768 B
    __shared__ __align__(16) float ws[DIM * WPITCH];        // 1280 B

    const int tid = threadIdx.x;

    // ---- Stage relation_emb (64 x 256 fp32) transposed+bf16+swizzled ----
    {
        const float4* rel4 = (const float4*)rel;
        #pragma unroll
        for (int i = 0; i < 8; ++i) {
            int vidx = i * 512 + tid;            // 4096 float4s total
            float4 v = rel4[vidx];
            int k0 = vidx * 4;                   // flat fp32 index
            int r  = k0 >> 8;
            int k  = k0 & 255;
            int d  = k >> 4;
            int e0 = k & 15;                     // e0 % 4 == 0 -> e0..e0+3 share e>>2
            int phys = ((d >> 2) + (e0 >> 2)) & 3;
            unsigned short* p = &rt[r * 256 + e0 * 16 + phys * 4 + (d & 3)];
            p[0]  = f2bf(v.x);
            p[16] = f2bf(v.y);
            p[32] = f2bf(v.z);
            p[48] = f2bf(v.w);
        }
        if (tid < 256) ws[(tid >> 4) * WPITCH + (tid & 15)] = W[tid];
    }
    __syncthreads();

    const int lane = tid & 63;
    const int wid  = tid >> 6;
    const int g    = lane >> 4;   // mem-group 0..3
    const int e    = lane & 15;   // dim index
    const int n    = blockIdx.x * 8 + wid;

    // Per-lane byte offsets into a relation's row for logical chunk j (swizzled)
    int voff[4];
    {
        const int s = e >> 2;
        #pragma unroll
        for (int j = 0; j < 4; ++j)
            voff[j] = e * 32 + (((j + s) & 3) << 3);
    }

    float item    = ent[nodes[n] * DIM + e];
    float out_acc = 0.f;

    #pragma unroll
    for (int hop = 0; hop < NHOP; ++hop) {
        // item vector -> wave-uniform scalars (SGPRs), no LDS-pipe shuffles
        float itm[16];
        #pragma unroll
        for (int d = 0; d < 16; ++d) itm[d] = bcast(item, d);

        const int ibase = hop * (NNODES * NMEM) + n * NMEM;
        float sc[8], tv[8];

        #pragma unroll
        for (int it = 0; it < 8; ++it) {
            const int m    = it * 4 + g;
            const int hidx = mh[ibase + m];
            const int ridx = mr[ibase + m];
            const int tidx = mt[ibase + m];

            const char* rbase = (const char*)rt + (ridx << 9);
            float q = 0.f;
            #pragma unroll
            for (int j = 0; j < 4; ++j) {
                uint2 u = *(const uint2*)(rbase + voff[j]);
                q += itm[4 * j + 0] * bflo(u.x) + itm[4 * j + 1] * bfhi(u.x)
                   + itm[4 * j + 2] * bflo(u.y) + itm[4 * j + 3] * bfhi(u.y);
            }
            float he = ent[hidx * DIM + e];
            sc[it] = dpp_sum16(q * he);          // score_m = item . (R @ h)
            tv[it] = ent[tidx * DIM + e];
        }

        // softmax over 32 slots — scores are small; skip the max pass
        float Z = 0.f;
        #pragma unroll
        for (int it = 0; it < 8; ++it) { sc[it] = __expf(sc[it]); Z += sc[it]; }
        Z += __shfl_xor(Z, 16);
        Z += __shfl_xor(Z, 32);
        const float inv = 1.f / Z;

        // o[e] = sum_m p_m * t_m[e]
        float o = 0.f;
        #pragma unroll
        for (int it = 0; it < 8; ++it) o += sc[it] * tv[it];
        o *= inv;
        o += __shfl_xor(o, 16);
        o += __shfl_xor(o, 32);

        out_acc += (hop == 0) ? 2.f * o : o;     // faithful: result = o1 + 2*o0

        // item = (item + o) @ W.T ; W row e from LDS (sc/tv dead here)
        const float v = item + o;
        float nit = 0.f;
        const float4* wr = (const float4*)&ws[e * WPITCH];
        #pragma unroll
        for (int j = 0; j < 4; ++j) {
            float4 w = wr[j];
            nit += w.x * bcast(v, 4 * j + 0) + w.y * bcast(v, 4 * j + 1)
                 + w.z * bcast(v, 4 * j + 2) + w.w * bcast(v, 4 * j + 3);
        }
        item = nit;
    }

    if (lane < 16) out[n * DIM + e] = out_acc;
}

extern "C" void kernel_launch(void* const* d_in, const int* in_sizes, int n_in,
                              void* d_out, int out_size, void* d_ws, size_t ws_size,
                              hipStream_t stream) {
    const int*   nodes = (const int*)d_in[0];
    const int*   mh    = (const int*)d_in[1];
    const int*   mr    = (const int*)d_in[2];
    const int*   mt    = (const int*)d_in[3];
    const float* ent   = (const float*)d_in[4];
    const float* rel   = (const float*)d_in[5];
    const float* W     = (const float*)d_in[6];
    float*       out   = (float*)d_out;

    dim3 grid(NNODES / 8);   // 1 wave per node, 8 nodes per 512-thread block
    dim3 block(512);
    ripple_kernel<<<grid, block, 0, stream>>>(nodes, mh, mr, mt, ent, rel, W, out);
}